// Round 1
// baseline (139.445 us; speedup 1.0000x reference)
//
#include <hip/hip_runtime.h>
#include <math.h>

// P2V: out[b,dhw] = top2-margin over n of softmax_n( |s2| * exp(-|s1| * dist[b,dhw,n]) )
// dist = |x|^2 + |g|^2 - 2 x.g  (same expansion as reference)
//
// Strategy:
//  - top-2 over n of v is top-2 of logit q (exp monotone) -> pass 1 has no exp.
//  - all math in exp2 domain: c1 = log2(e)*|s1| folded into a per-n table
//    A[n] = {-c1*|x_n|^2, 2c1*x, 2c1*y, 2c1*z} staged in LDS (16 KB, per-b).
//  - per-thread constant Ct = |s2| * exp2(-c1*|g|^2); v_n = Ct * exp2(q_n).
//  - pass 2: S = sum_n exp2( ECt*exp2(q_n) - ECt*u0 ), ECt = log2(e)*Ct.
//  - out = (1 - exp2(ECt*(u1-u0))) / S.
// One thread per output element; 512 blocks x 256 threads; LDS reads are
// wave-uniform broadcasts (conflict-free).

#define LOG2E 1.44269504088896340736f

__global__ __launch_bounds__(256, 2) void p2v_kernel(
    const float* __restrict__ xyz,   // (B=4, C=3, N=1024)
    const float* __restrict__ grid,  // (C=3, D*H*W=32768)
    const float* __restrict__ s1,
    const float* __restrict__ s2,
    float* __restrict__ out)         // (B=4, 32768)
{
    __shared__ float4 A[1024];       // 16 KB per-n table for this block's b

    const int tid = threadIdx.x;
    const int b   = blockIdx.x >> 7;                 // 128 blocks per b
    const int dhw = ((blockIdx.x & 127) << 8) + tid; // coalesced

    const float s1a = fabsf(s1[0]);
    const float s2a = fabsf(s2[0]);
    const float c1  = LOG2E * s1a;

    // Stage per-n table: A[n] = { -c1*|x|^2, 2c1*x, 2c1*y, 2c1*z }
    const float* xb = xyz + b * 3072;
    #pragma unroll
    for (int i = 0; i < 4; ++i) {
        const int n = tid + i * 256;
        const float x = xb[n], y = xb[1024 + n], z = xb[2048 + n];
        const float x2 = fmaf(x, x, fmaf(y, y, z * z));
        A[n] = make_float4(-c1 * x2, 2.f * c1 * x, 2.f * c1 * y, 2.f * c1 * z);
    }
    __syncthreads();

    const float g0 = grid[dhw];
    const float g1 = grid[32768 + dhw];
    const float g2 = grid[65536 + dhw];
    const float baseE = -c1 * fmaf(g0, g0, fmaf(g1, g1, g2 * g2));
    const float Ct  = s2a * exp2f(baseE);   // v_n = Ct * exp2(q_n)
    const float ECt = LOG2E * Ct;

    // ---- pass 1: branchless top-2 of q_n (no transcendentals) ----
    float t0 = -INFINITY, t1 = -INFINITY;
    #pragma unroll 8
    for (int n = 0; n < 1024; ++n) {
        const float4 a = A[n];
        const float q = fmaf(g0, a.y, fmaf(g1, a.z, fmaf(g2, a.w, a.x)));
        t1 = __builtin_amdgcn_fmed3f(t0, t1, q);  // new 2nd-largest
        t0 = fmaxf(t0, q);                        // new largest
    }

    const float u0   = exp2f(t0);
    const float mEv0 = -(ECt * u0);   // -log2(e)*v_max

    // ---- pass 2: S = sum_n exp(v_n - v0), two partials ----
    float S0 = 0.f, S1 = 0.f;
    #pragma unroll 4
    for (int n = 0; n < 1024; n += 2) {
        const float4 a = A[n];
        const float4 c = A[n + 1];
        const float qa = fmaf(g0, a.y, fmaf(g1, a.z, fmaf(g2, a.w, a.x)));
        const float qb = fmaf(g0, c.y, fmaf(g1, c.z, fmaf(g2, c.w, c.x)));
        S0 += exp2f(fmaf(ECt, exp2f(qa), mEv0));
        S1 += exp2f(fmaf(ECt, exp2f(qb), mEv0));
    }
    const float S = S0 + S1;

    const float u1  = exp2f(t1);
    const float num = 1.f - exp2f(ECt * (u1 - u0));  // 1 - exp(v1 - v0)
    out[b * 32768 + dhw] = num / S;
}

extern "C" void kernel_launch(void* const* d_in, const int* in_sizes, int n_in,
                              void* d_out, int out_size, void* d_ws, size_t ws_size,
                              hipStream_t stream) {
    const float* xyz  = (const float*)d_in[0];
    const float* grid = (const float*)d_in[1];
    const float* s1   = (const float*)d_in[2];
    const float* s2   = (const float*)d_in[3];
    float* out        = (float*)d_out;
    hipLaunchKernelGGL(p2v_kernel, dim3(512), dim3(256), 0, stream,
                       xyz, grid, s1, s2, out);
}

// Round 2
// 99.976 us; speedup vs baseline: 1.3948x; 1.3948x over previous
//
#include <hip/hip_runtime.h>
#include <math.h>

// P2V: out[b,dhw] = top2-margin over n of softmax_n( |s2| * exp(-|s1| * dist) )
// dist = |x|^2 + |g|^2 - 2 x.g
//
// Single fused pass:
//  - q_n = -c1*|x_n|^2 + 2c1*(x_n . g)  with c1 = log2(e)*|s1|; v_n = Ct*2^q_n,
//    Ct = |s2|*2^(-c1*|g|^2).
//  - top-2 of v == top-2 of q (monotone) -> branchless med3/max tracking.
//  - softmax shift uses the BOUND v_n <= |s2| (dist>=0), so no max pre-pass:
//    S = sum_n 2^(ECt*2^(q_n) - Ls2), ECt = log2e*Ct, Ls2 = log2e*|s2|.
//  - out = 2^(ECt*u0 - Ls2) * (1 - 2^(ECt*(u1-u0))) / S,  u_i = 2^(t_i).
// Per n: 1 ds_read_b128 (wave-uniform broadcast) + 7 VALU + 2 v_exp_f32.
// 8-deep explicit load batching keeps >=8 LDS reads in flight.

#define LOG2E 1.44269504088896340736f

__global__ __launch_bounds__(256, 2) void p2v_kernel(
    const float* __restrict__ xyz,   // (B=4, C=3, N=1024)
    const float* __restrict__ grid,  // (C=3, 32768)
    const float* __restrict__ s1,
    const float* __restrict__ s2,
    float* __restrict__ out)         // (B=4, 32768)
{
    __shared__ float4 A[1024];       // 16 KB per-n table for this block's b

    const int tid = threadIdx.x;
    const int b   = blockIdx.x >> 7;                 // 128 blocks per b
    const int dhw = ((blockIdx.x & 127) << 8) + tid; // coalesced

    const float s1a = fabsf(s1[0]);
    const float s2a = fabsf(s2[0]);
    const float c1  = LOG2E * s1a;
    const float Ls2 = LOG2E * s2a;

    // Stage per-n table: A[n] = { -c1*|x|^2, 2c1*x, 2c1*y, 2c1*z }
    const float* xb = xyz + b * 3072;
    #pragma unroll
    for (int i = 0; i < 4; ++i) {
        const int n = tid + i * 256;
        const float x = xb[n], y = xb[1024 + n], z = xb[2048 + n];
        const float x2 = fmaf(x, x, fmaf(y, y, z * z));
        A[n] = make_float4(-c1 * x2, 2.f * c1 * x, 2.f * c1 * y, 2.f * c1 * z);
    }
    __syncthreads();

    const float g0 = grid[dhw];
    const float g1 = grid[32768 + dhw];
    const float g2 = grid[65536 + dhw];
    const float Ct  = s2a * __builtin_amdgcn_exp2f(-c1 * fmaf(g0, g0, fmaf(g1, g1, g2 * g2)));
    const float ECt = LOG2E * Ct;

    float t0 = -INFINITY, t1 = -INFINITY;
    float S0 = 0.f, S1 = 0.f, S2 = 0.f, S3 = 0.f;

    for (int n0 = 0; n0 < 1024; n0 += 8) {
        float4 r[8];
        #pragma unroll
        for (int j = 0; j < 8; ++j) r[j] = A[n0 + j];   // 8 reads in flight
        #pragma unroll
        for (int j = 0; j < 8; ++j) {
            const float4 a = r[j];
            const float q = fmaf(g0, a.y, fmaf(g1, a.z, fmaf(g2, a.w, a.x)));
            t1 = __builtin_amdgcn_fmed3f(t0, t1, q);   // new 2nd-largest
            t0 = fmaxf(t0, q);                         // new largest
            const float w = __builtin_amdgcn_exp2f(
                fmaf(ECt, __builtin_amdgcn_exp2f(q), -Ls2));
            if (j == 0) S0 += w; else if (j == 1) S1 += w;
            else if (j == 2) S2 += w; else if (j == 3) S3 += w;
            else if (j == 4) S0 += w; else if (j == 5) S1 += w;
            else if (j == 6) S2 += w; else S3 += w;
        }
    }
    const float S = (S0 + S1) + (S2 + S3);

    const float u0 = __builtin_amdgcn_exp2f(t0);
    const float u1 = __builtin_amdgcn_exp2f(t1);
    const float w0 = __builtin_amdgcn_exp2f(fmaf(ECt, u0, -Ls2)); // exp(v0-|s2|)
    const float num = w0 * (1.f - __builtin_amdgcn_exp2f(ECt * (u1 - u0)));
    out[b * 32768 + dhw] = num / S;
}

extern "C" void kernel_launch(void* const* d_in, const int* in_sizes, int n_in,
                              void* d_out, int out_size, void* d_ws, size_t ws_size,
                              hipStream_t stream) {
    const float* xyz  = (const float*)d_in[0];
    const float* grid = (const float*)d_in[1];
    const float* s1   = (const float*)d_in[2];
    const float* s2   = (const float*)d_in[3];
    float* out        = (float*)d_out;
    hipLaunchKernelGGL(p2v_kernel, dim3(512), dim3(256), 0, stream,
                       xyz, grid, s1, s2, out);
}